// Round 9
// baseline (1521.742 us; speedup 1.0000x reference)
//
#include <hip/hip_runtime.h>
#include <hip/hip_bf16.h>

typedef __bf16 bf16x8 __attribute__((ext_vector_type(8)));
typedef float  f32x4  __attribute__((ext_vector_type(4)));
typedef float  f32x2  __attribute__((ext_vector_type(2)));
typedef unsigned int u32x4 __attribute__((ext_vector_type(4)));
typedef unsigned short ushort_t;
static_assert(sizeof(bf16x8) == 16, "bf16x8 must be 16B");

#define DEV __device__ __forceinline__

DEV f32x4 mfma16(bf16x8 a, bf16x8 b, f32x4 c) {
    return __builtin_amdgcn_mfma_f32_16x16x32_bf16(a, b, c, 0, 0, 0);
}
DEV f32x4 mfma8(long a, long b, f32x4 c) {
    return __builtin_amdgcn_mfma_f32_16x16x32_fp8_fp8(a, b, c, 0, 0, 0);
}
DEV float sigm(float x)   { return 1.0f / (1.0f + __expf(-x)); }
DEV float tanh_f(float x) { return 2.0f / (1.0f + __expf(-2.0f * x)) - 1.0f; }

// async global->LDS, 16B per lane; lds dest must be wave-uniform base (+lane*16)
DEV void glds16(const __hip_bfloat16* g, __hip_bfloat16* l) {
    __builtin_amdgcn_global_load_lds(
        (const __attribute__((address_space(1))) unsigned int*)g,
        (__attribute__((address_space(3))) unsigned int*)l, 16, 0, 0);
}

DEV unsigned char f32_to_fp8(float v) {
    int p = __builtin_amdgcn_cvt_pk_fp8_f32(v, v, 0, false);
    return (unsigned char)(p & 0xFF);
}

DEV int i4get(const int4& v, int r) {
    return r == 0 ? v.x : r == 1 ? v.y : r == 2 ? v.z : v.w;
}

// ---------------- dtype detection: 1 = inputs are bf16, 0 = inputs are fp32 --
__global__ __launch_bounds__(128) void kdetect(const unsigned int* __restrict__ raw,
                                               int* __restrict__ mode) {
    __shared__ int cnt;
    if (threadIdx.x == 0) cnt = 0;
    __syncthreads();
    unsigned int w = raw[threadIdx.x];
    unsigned short lo = (unsigned short)(w & 0xFFFFu);
    unsigned int f32bits = ((unsigned int)lo) << 16;
    float v;
    __builtin_memcpy(&v, &f32bits, 4);
    float a = fabsf(v);
    if (a >= 1e-4f && a <= 1.0f) atomicAdd(&cnt, 1);
    __syncthreads();
    if (threadIdx.x == 0) *mode = (cnt >= 64) ? 1 : 0;
}

// ---------------- fused dtype conversions (6 segments in one launch) ---------
struct CvtArgs {
    const void* src[6];
    void* dst[6];
    int n[6];
    int bf16out[6];
};
__global__ __launch_bounds__(256) void kcvt_all(CvtArgs a, const int* __restrict__ mode) {
    int seg = blockIdx.y;
    int i = blockIdx.x * 256 + threadIdx.x;
    if (i >= a.n[seg]) return;
    int m = *mode;
    if (a.bf16out[seg]) {
        __hip_bfloat16* d = (__hip_bfloat16*)a.dst[seg];
        d[i] = m ? ((const __hip_bfloat16*)a.src[seg])[i]
                 : __float2bfloat16(((const float*)a.src[seg])[i]);
    } else {
        float* d = (float*)a.dst[seg];
        d[i] = m ? __bfloat162float(((const __hip_bfloat16*)a.src[seg])[i])
                 : ((const float*)a.src[seg])[i];
    }
}

// ---------- fused tiled transpose+convert: 8 tensors in one launch -----------
// out_bf16[c][r] = (bf16)in[r][c]; blockIdx.z selects the tensor.
struct TransArgs {
    const void* src[8];
    __hip_bfloat16* dst[8];
    int R[8];
    int C[8];
};
__global__ __launch_bounds__(256) void ktrans_all(TransArgs a, const int* __restrict__ mode) {
    __shared__ float tile[64][65];
    int id = blockIdx.z;
    int R = a.R[id], C = a.C[id];
    int c0 = blockIdx.x * 64, r0 = blockIdx.y * 64;
    if (c0 >= C || r0 >= R) return;
    const void* src = a.src[id];
    __hip_bfloat16* out = a.dst[id];
    int tx = threadIdx.x & 63, ty = threadIdx.x >> 6;
    int m = *mode;
#pragma unroll
    for (int i = ty; i < 64; i += 4) {
        size_t ix = (size_t)(r0 + i) * C + (c0 + tx);
        tile[i][tx] = m ? __bfloat162float(((const __hip_bfloat16*)src)[ix])
                        : ((const float*)src)[ix];
    }
    __syncthreads();
#pragma unroll
    for (int i = ty; i < 64; i += 4)
        out[(size_t)(c0 + i) * R + (r0 + tx)] = __float2bfloat16(tile[tx][i]);
}

// ---- fused prep: blocks 0..255 = Gtab (E@Wi + b), 256..287 = VX (fe@vWi+vb) --
__global__ __launch_bounds__(256) void kprep_all(
    const __hip_bfloat16* __restrict__ E,     // [128][128]
    const __hip_bfloat16* __restrict__ WiT,   // [2][2048][256]
    const float* __restrict__ bF,
    const float* __restrict__ bB,
    float* __restrict__ G,                    // [4][128][512][4]
    const __hip_bfloat16* __restrict__ fe,    // [32][1024]
    const __hip_bfloat16* __restrict__ vWiT,  // [4096][1024]
    const float* __restrict__ vb,             // [4096]
    float* __restrict__ VX)                   // [32][4096]
{
    int lane = threadIdx.x & 63, wid = threadIdx.x >> 6;
    int r16 = lane & 15, quad = lane >> 4;

    if (blockIdx.x < 256) {
        int bid = blockIdx.x;
        int dh = bid >> 6;
        int dir = dh >> 1, half = dh & 1;
        int m0 = ((bid >> 5) & 1) * 64;
        int n0 = (bid & 31) * 64;
        int wrow = wid >> 1, wcol = wid & 1;

        f32x4 acc[2][2] = {};
        const __hip_bfloat16* Ap = E + (size_t)(m0 + wrow * 32 + r16) * 128 + quad * 8;
        const __hip_bfloat16* Bp = WiT + (size_t)dir * 2048 * 256
                                 + (size_t)(n0 + wcol * 32 + r16) * 256 + half * 128 + quad * 8;
#pragma unroll
        for (int kb = 0; kb < 128; kb += 32) {
            bf16x8 a0 = *(const bf16x8*)(Ap + kb);
            bf16x8 a1 = *(const bf16x8*)(Ap + 16 * 128 + kb);
            bf16x8 b0 = *(const bf16x8*)(Bp + kb);
            bf16x8 b1 = *(const bf16x8*)(Bp + 16 * 256 + kb);
            acc[0][0] = mfma16(a0, b0, acc[0][0]);
            acc[0][1] = mfma16(a0, b1, acc[0][1]);
            acc[1][0] = mfma16(a1, b0, acc[1][0]);
            acc[1][1] = mfma16(a1, b1, acc[1][1]);
        }
        const float* bias = dir ? bB : bF;
        float* Gt = G + (size_t)dh * 128 * 2048;
#pragma unroll
        for (int rt = 0; rt < 2; rt++)
#pragma unroll
            for (int ct = 0; ct < 2; ct++)
#pragma unroll
                for (int r = 0; r < 4; r++) {
                    int mm = m0 + wrow * 32 + rt * 16 + quad * 4 + r;
                    int j = n0 + wcol * 32 + ct * 16 + r16;
                    float v = acc[rt][ct][r];
                    if (half == 0) v += bias[j];
                    int g = j >> 9, u = j & 511;
                    Gt[((size_t)mm * 512 + u) * 4 + g] = v;
                }
    } else {
        int n0 = (blockIdx.x - 256) * 128;
        f32x4 acc[2][2] = {};
        const __hip_bfloat16* Ap = fe + (size_t)r16 * 1024 + quad * 8;
        const __hip_bfloat16* Bp = vWiT + (size_t)(n0 + wid * 32 + r16) * 1024 + quad * 8;
        for (int kb = 0; kb < 1024; kb += 32) {
            bf16x8 a0 = *(const bf16x8*)(Ap + kb);
            bf16x8 a1 = *(const bf16x8*)(Ap + 16 * 1024 + kb);
            bf16x8 b0 = *(const bf16x8*)(Bp + kb);
            bf16x8 b1 = *(const bf16x8*)(Bp + 16 * 1024 + kb);
            acc[0][0] = mfma16(a0, b0, acc[0][0]);
            acc[0][1] = mfma16(a0, b1, acc[0][1]);
            acc[1][0] = mfma16(a1, b0, acc[1][0]);
            acc[1][1] = mfma16(a1, b1, acc[1][1]);
        }
#pragma unroll
        for (int rt = 0; rt < 2; rt++)
#pragma unroll
            for (int ct = 0; ct < 2; ct++)
#pragma unroll
                for (int r = 0; r < 4; r++) {
                    int m = rt * 16 + quad * 4 + r;
                    int j = n0 + wid * 32 + ct * 16 + r16;
                    VX[(size_t)m * 4096 + j] = acc[rt][ct][r] + vb[j];
                }
    }
}

// ======== encoder LSTM step: 512 blocks (dir x 16 mt x 16 us), 64m x 32u =====
// Triple-buffered counted-vmcnt pipeline + epilogue prefetch (verified r6-r8).
__global__ __launch_bounds__(256, 2) void kenc_step(
    int t,
    const __hip_bfloat16* __restrict__ WhT,   // [2][2048][512]
    const float* __restrict__ Gtab,           // [4][128][512][4]
    const int* __restrict__ exs,
    const int* __restrict__ cls,
    const __hip_bfloat16* __restrict__ h_in,  // [2][1024][512]
    __hip_bfloat16* __restrict__ h_out,
    float* __restrict__ c_st,                 // [2][1024][512]
    unsigned char* __restrict__ ctx8)         // [64][256][4][1024] fp8 (x16)
{
    __shared__ __align__(16) __hip_bfloat16 sA[3][64 * 64];   // 3 x 8KB
    __shared__ __align__(16) __hip_bfloat16 sB[3][128 * 64];  // 3 x 16KB

    int bid = blockIdx.x;
    int dir = bid >> 8;
    int mt  = (bid >> 4) & 15;
    int us  = bid & 15;
    int l = dir ? (63 - t) : t;
    int m0 = mt * 64, u0 = us * 32;

    int lane = threadIdx.x & 63, w = threadIdx.x >> 6;   // 4 waves
    int wm = w >> 1, wu = w & 1;                          // 2m x 2u
    int r16 = lane & 15, quad = lane >> 4;
    int srow = lane >> 3;
    int scol = ((lane & 7) ^ srow) * 8;   // swizzled global source column

    const __hip_bfloat16* Ab = h_in + (size_t)dir * 1024 * 512;
    const __hip_bfloat16* Bb = WhT + (size_t)dir * 2048 * 512;

    int u = u0 + wu * 16 + r16;
    int mbase = m0 + wm * 32;
    size_t cbase = (size_t)dir * 1024 * 512;
    const float* GeT = Gtab + (size_t)(dir * 2) * 128 * 2048;
    const float* GcT = GeT + 128 * 2048;

    // token prefetch (fast L2 loads; retire before iter-0's counted wait)
    int4 tE0 = *(const int4*)&exs[l * 1024 + mbase + quad * 4];
    int4 tE1 = *(const int4*)&exs[l * 1024 + mbase + 16 + quad * 4];
    int4 tC0 = *(const int4*)&cls[l * 1024 + mbase + quad * 4];
    int4 tC1 = *(const int4*)&cls[l * 1024 + mbase + 16 + quad * 4];

    f32x4 acc[4][2] = {};  // [gate][mi]
    f32x4 geP[2][4], gcP[2][4];
    float cP[2][4];

    auto stage = [&](int buf, int it) {
        int kb = it * 64;
#pragma unroll
        for (int c = 0; c < 2; c++) {
            int r8 = (w * 2 + c) * 8;
            glds16(Ab + (size_t)(m0 + r8 + srow) * 512 + kb + scol,
                   &sA[buf][r8 * 64]);
        }
#pragma unroll
        for (int c = 0; c < 4; c++) {
            int rl = (w * 4 + c) * 8;
            int rr = rl + srow;
            int g = rr >> 5, j = rr & 31;
            glds16(Bb + (size_t)(g * 512 + u0 + j) * 512 + kb + scol,
                   &sB[buf][rl * 64]);
        }
    };

    // prologue: 2 K-tiles in flight (6 ops each per wave)
    stage(0, 0);
    stage(1, 1);

    const int sw = r16 & 7;
    const int NIT = 8;  // 512/64
#pragma unroll
    for (int it = 0; it < NIT; it++) {
        if (it < NIT - 1)
            asm volatile("s_waitcnt vmcnt(6) lgkmcnt(0)" ::: "memory");
        else
            asm volatile("s_waitcnt vmcnt(24) lgkmcnt(0)" ::: "memory");
        __builtin_amdgcn_s_barrier();
        if (it + 2 < NIT) {
            stage((it + 2) % 3, it + 2);
        } else if (it == NIT - 2) {
            // issue epilogue loads: 16 Gtab gathers + 8 c_st reads (24 VMEM)
#pragma unroll
            for (int mi = 0; mi < 2; mi++)
#pragma unroll
                for (int r = 0; r < 4; r++) {
                    int vE = i4get(mi ? tE1 : tE0, r);
                    int vC = i4get(mi ? tC1 : tC0, r);
                    geP[mi][r] = *(const f32x4*)&GeT[((size_t)vE * 512 + u) * 4];
                    gcP[mi][r] = *(const f32x4*)&GcT[((size_t)vC * 512 + u) * 4];
                    int m = mbase + mi * 16 + quad * 4 + r;
                    cP[mi][r] = c_st[cbase + (size_t)m * 512 + u];
                }
        }
        const int buf = it % 3;   // compile-time after full unroll
#pragma unroll
        for (int k32 = 0; k32 < 64; k32 += 32) {
            int co = (((k32 >> 3) + quad) ^ sw) * 8;   // swizzled ds_read column
            bf16x8 a[2], bf[4];
#pragma unroll
            for (int mi = 0; mi < 2; mi++)
                a[mi] = *(const bf16x8*)&sA[buf][(wm * 32 + mi * 16 + r16) * 64 + co];
#pragma unroll
            for (int g = 0; g < 4; g++)
                bf[g] = *(const bf16x8*)&sB[buf][(g * 32 + wu * 16 + r16) * 64 + co];
#pragma unroll
            for (int g = 0; g < 4; g++)
#pragma unroll
                for (int mi = 0; mi < 2; mi++)
                    acc[g][mi] = mfma16(a[mi], bf[g], acc[g][mi]);
        }
    }

    // epilogue: thread owns u, 8 m's; all inputs prefetched
#pragma unroll
    for (int mi = 0; mi < 2; mi++)
#pragma unroll
        for (int r = 0; r < 4; r++) {
            int m = mbase + mi * 16 + quad * 4 + r;
            f32x4 ge = geP[mi][r];
            f32x4 gc = gcP[mi][r];
            float gi = acc[0][mi][r] + ge[0] + gc[0];
            float gf = acc[1][mi][r] + ge[1] + gc[1];
            float gg = acc[2][mi][r] + ge[2] + gc[2];
            float go = acc[3][mi][r] + ge[3] + gc[3];
            size_t cix = cbase + (size_t)m * 512 + u;
            float cn = sigm(gf) * cP[mi][r] + sigm(gi) * tanh_f(gg);
            c_st[cix] = cn;
            float hn = sigm(go) * tanh_f(cn);
            h_out[cix] = __float2bfloat16(hn);
            ctx8[(((size_t)l * 256 + (m >> 2)) * 4 + (m & 3)) * 1024 + dir * 512 + u]
                = f32_to_fp8(hn * 16.0f);
        }
}

// ---- fused: fp8 ctx transpose (blocks 0..16383) + decoder init (16384..17407)
__global__ __launch_bounds__(256) void ktrans8_init(
    const unsigned char* __restrict__ ctx8,
    unsigned char* __restrict__ ctxT8,
    const __hip_bfloat16* __restrict__ hf,  // final h (buf0): [2][1024][512]
    const float* __restrict__ cf,
    __hip_bfloat16* __restrict__ h0,        // [256][1024] (hAll[0])
    float* __restrict__ c0)
{
    __shared__ unsigned int tile[64][17];
    int bx = blockIdx.x;
    int tid = threadIdx.x;
    if (bx < 16384) {
        int b4n = bx & 1023;
        int e0 = (bx >> 10) * 64;
#pragma unroll
        for (int pass = 0; pass < 4; pass++) {
            int idx = pass * 256 + tid;
            int l = idx >> 4, c = idx & 15;
            tile[l][c] = *(const unsigned int*)(ctx8 + (size_t)l * (1024 * 1024)
                                                + (size_t)b4n * 1024 + e0 + c * 4);
        }
        __syncthreads();
        const unsigned char* tb = (const unsigned char*)tile;
#pragma unroll
        for (int pass = 0; pass < 4; pass++) {
            int idx = pass * 256 + tid;
            int e = idx >> 4, c = idx & 15;
            unsigned int v = 0;
#pragma unroll
            for (int j = 0; j < 4; j++) {
                unsigned int byte = tb[(size_t)(c * 4 + j) * 68 + e];
                v |= byte << (8 * j);
            }
            *(unsigned int*)(ctxT8 + ((size_t)b4n * 1024 + e0 + e) * 64 + c * 4) = v;
        }
    } else {
        int idx = (bx - 16384) * 256 + tid;
        int b = idx >> 10, e = idx & 1023;
        int dir = e >> 9, u = e & 511;
        const __hip_bfloat16* hs = hf + (size_t)dir * 1024 * 512;
        const float* cs = cf + (size_t)dir * 1024 * 512;
        float hv = -3.4e38f, cv = -3.4e38f;
#pragma unroll
        for (int n = 0; n < 4; n++) {
            size_t ix = (size_t)(b * 4 + n) * 512 + u;
            hv = fmaxf(hv, __bfloat162float(hs[ix]));
            cv = fmaxf(cv, cs[ix]);
        }
        h0[idx] = __float2bfloat16(hv);
        c0[idx] = cv;
    }
}

// ======== decoder fused GEMM: cell (0..127: 64m x 32u) + q (128..255) ========
// Cell: counted-vmcnt pipeline + epilogue prefetch. Q: counted vmcnt(3).
__global__ __launch_bounds__(256, 2) void kdec_gemm(
    int t,
    const __hip_bfloat16* __restrict__ vWhT,   // [4096][1024]
    const __hip_bfloat16* __restrict__ WattnT, // [1024][1024]
    const float* __restrict__ VX,              // [32][4096]
    const __hip_bfloat16* __restrict__ h_in,   // [256][1024]  (h_t = hAll[t])
    __hip_bfloat16* __restrict__ h_out,        // [256][1024]  (hAll[t+1])
    float* __restrict__ c_st,                  // [256][1024]
    float* __restrict__ qout)                  // [256][1024]  (qall[t])
{
    __shared__ __align__(16) __hip_bfloat16 sA[3][64 * 64];   // 3 x 8KB
    __shared__ __align__(16) __hip_bfloat16 sB[3][128 * 64];  // 3 x 16KB

    int bid = blockIdx.x;
    int lane = threadIdx.x & 63, w = threadIdx.x >> 6;   // 4 waves
    int wm = w >> 1, wu = w & 1;                          // 2m x 2u/2n
    int r16 = lane & 15, quad = lane >> 4;
    int srow = lane >> 3;
    int scol = ((lane & 7) ^ srow) * 8;   // swizzled global source column
    const int NIT = 16;  // 1024/64
    const int sw = r16 & 7;

    bool cellp = bid < 128;
    int b2 = cellp ? bid : bid - 128;
    int m0 = (b2 >> 5) * 64;       // 4 m-tiles of 64
    int n0 = (b2 & 31) * 32;       // 32 u/n-tiles of 32
    int u = n0 + wu * 16 + r16;
    int mbase = m0 + wm * 32;

    if (cellp) {
        f32x4 acc[4][2] = {};
        float vxP[4], cP[2][4];
        const float* vx = VX + (size_t)t * 4096;
        auto stage = [&](int buf, int it) {
            int kb = it * 64;
#pragma unroll
            for (int c = 0; c < 2; c++) {
                int r8 = (w * 2 + c) * 8;
                glds16(h_in + (size_t)(m0 + r8 + srow) * 1024 + kb + scol,
                       &sA[buf][r8 * 64]);
            }
#pragma unroll
            for (int c = 0; c < 4; c++) {
                int rl = (w * 4 + c) * 8;
                int rr = rl + srow;
                int g = rr >> 5, j = rr & 31;
                glds16(vWhT + (size_t)(g * 1024 + n0 + j) * 1024 + kb + scol,
                       &sB[buf][rl * 64]);
            }
        };
        stage(0, 0);
        stage(1, 1);
#pragma unroll
        for (int it = 0; it < NIT; it++) {
            if (it < NIT - 1)
                asm volatile("s_waitcnt vmcnt(6) lgkmcnt(0)" ::: "memory");
            else
                asm volatile("s_waitcnt vmcnt(12) lgkmcnt(0)" ::: "memory");
            __builtin_amdgcn_s_barrier();
            if (it + 2 < NIT) {
                stage((it + 2) % 3, it + 2);
            } else if (it == NIT - 2) {
                // issue epilogue loads: 4 VX + 8 c_st (12 VMEM)
                vxP[0] = vx[u];
                vxP[1] = vx[1024 + u];
                vxP[2] = vx[2048 + u];
                vxP[3] = vx[3072 + u];
#pragma unroll
                for (int mi = 0; mi < 2; mi++)
#pragma unroll
                    for (int r = 0; r < 4; r++) {
                        int m = mbase + mi * 16 + quad * 4 + r;
                        cP[mi][r] = c_st[(size_t)m * 1024 + u];
                    }
            }
            const int buf = it % 3;
#pragma unroll
            for (int k32 = 0; k32 < 64; k32 += 32) {
                int co = (((k32 >> 3) + quad) ^ sw) * 8;
                bf16x8 a[2], bf[4];
#pragma unroll
                for (int mi = 0; mi < 2; mi++)
                    a[mi] = *(const bf16x8*)&sA[buf][(wm * 32 + mi * 16 + r16) * 64 + co];
#pragma unroll
                for (int g = 0; g < 4; g++)
                    bf[g] = *(const bf16x8*)&sB[buf][(g * 32 + wu * 16 + r16) * 64 + co];
#pragma unroll
                for (int g = 0; g < 4; g++)
#pragma unroll
                    for (int mi = 0; mi < 2; mi++)
                        acc[g][mi] = mfma16(a[mi], bf[g], acc[g][mi]);
            }
        }
#pragma unroll
        for (int mi = 0; mi < 2; mi++)
#pragma unroll
            for (int r = 0; r < 4; r++) {
                int m = mbase + mi * 16 + quad * 4 + r;
                float gi = acc[0][mi][r] + vxP[0];
                float gf = acc[1][mi][r] + vxP[1];
                float gg = acc[2][mi][r] + vxP[2];
                float go = acc[3][mi][r] + vxP[3];
                size_t cix = (size_t)m * 1024 + u;
                float cn = sigm(gf) * cP[mi][r] + sigm(gi) * tanh_f(gg);
                c_st[cix] = cn;
                h_out[cix] = __float2bfloat16(sigm(go) * tanh_f(cn));
            }
    } else {
        f32x4 acc[2] = {};
        auto stage = [&](int buf, int it) {
            int kb = it * 64;
#pragma unroll
            for (int c = 0; c < 2; c++) {
                int r8 = (w * 2 + c) * 8;
                glds16(h_in + (size_t)(m0 + r8 + srow) * 1024 + kb + scol,
                       &sA[buf][r8 * 64]);
            }
            {
                int rl = w * 8;
                glds16(WattnT + (size_t)(n0 + rl + srow) * 1024 + kb + scol,
                       &sB[buf][rl * 64]);
            }
        };
        stage(0, 0);
        stage(1, 1);
#pragma unroll
        for (int it = 0; it < NIT; it++) {
            if (it < NIT - 1)
                asm volatile("s_waitcnt vmcnt(3) lgkmcnt(0)" ::: "memory");
            else
                asm volatile("s_waitcnt vmcnt(0) lgkmcnt(0)" ::: "memory");
            __builtin_amdgcn_s_barrier();
            if (it + 2 < NIT) stage((it + 2) % 3, it + 2);
            const int buf = it % 3;
#pragma unroll
            for (int k32 = 0; k32 < 64; k32 += 32) {
                int co = (((k32 >> 3) + quad) ^ sw) * 8;
                bf16x8 a[2];
#pragma unroll
                for (int mi = 0; mi < 2; mi++)
                    a[mi] = *(const bf16x8*)&sA[buf][(wm * 32 + mi * 16 + r16) * 64 + co];
                bf16x8 bf = *(const bf16x8*)&sB[buf][(wu * 16 + r16) * 64 + co];
#pragma unroll
                for (int mi = 0; mi < 2; mi++)
                    acc[mi] = mfma16(a[mi], bf, acc[mi]);
            }
        }
        int n = n0 + wu * 16 + r16;
#pragma unroll
        for (int mi = 0; mi < 2; mi++)
#pragma unroll
            for (int r = 0; r < 4; r++) {
                int m = mbase + mi * 16 + quad * 4 + r;
                qout[(size_t)m * 1024 + n] = acc[mi][r];
            }
    }
}

// ======== MFMA attention: block = b, all 32 t batched ========================
// LDS phase-aliased (peak 75520 B -> 2 blocks/CU, was 147KB @ 1 block/CU):
//   phaseQ/G1: sQ8[0,33024) sS[33024,66304) ; softmax: sS + sP[66304,75520)
//   G2: sPool[0,66048) (aliases sQ8+sS, dead) + sP ; G3: sPool + slg[66304,..)
// Barriers between phases already order the aliased lifetimes.
__global__ __launch_bounds__(512, 4) void kattn_mfma(
    const float* __restrict__ qall,           // [32][256][1024]
    const unsigned char* __restrict__ ctx8,   // [64][1024][1024] fp8 (x16)
    const unsigned char* __restrict__ ctxT8,  // [1024][1024][64] fp8 (x16)
    const __hip_bfloat16* __restrict__ hAll,  // [33][256][1024]
    const __hip_bfloat16* __restrict__ WcT,   // [64][2048]
    const float* __restrict__ bcomp,          // [64]
    const int* __restrict__ actions,          // [256][32]
    float* __restrict__ nllT)                 // [32][256]
{
    __shared__ __align__(16) char smem[75520];
    unsigned char* sQ8   = (unsigned char*)smem;             // 32*1032, stride 1032
    float*         sS    = (float*)(smem + 33024);           // [n*32+t][65]
    unsigned char* sP    = (unsigned char*)(smem + 66304);   // 4*32*72
    ushort_t*      sPool = (ushort_t*)smem;                  // 32*1032 (aliases sQ8+sS)
    float*         slg   = (float*)(smem + 66304);           // 32*68 (aliases sP)

    int b = blockIdx.x;
    int tid = threadIdx.x;
    int lane = tid & 63, w = tid >> 6;
    int r16 = lane & 15, quad = lane >> 4;
    const size_t LSTR = 1024 * 1024;

    // ---- phase Q: qall fp32 -> fp8 (x 1/4) into LDS
    for (int i = 0; i < 64; i++) {
        int idx = i * 512 + tid;           // coalesced over tid
        int t = idx >> 10, e = idx & 1023;
        float v = qall[((size_t)t * 256 + b) * 1024 + e] * 0.25f;
        sQ8[t * 1032 + e] = f32_to_fp8(v);
    }
    __syncthreads();

    // ---- GEMM1: wave w -> (n = w>>1, l-half lh = w&1)
    {
        int n = w >> 1, lh = w & 1;
        int l0 = lh * 32;
        f32x4 c[2][2] = {};
        const unsigned char* cbase = ctx8 + (size_t)(b * 4 + n) * 1024;
        for (int k0 = 0; k0 < 1024; k0 += 32) {
            long a[2], bv[2];
#pragma unroll
            for (int mt = 0; mt < 2; mt++)
                __builtin_memcpy(&a[mt], &sQ8[(mt * 16 + r16) * 1032 + k0 + quad * 8], 8);
#pragma unroll
            for (int lt = 0; lt < 2; lt++)
                bv[lt] = *(const long*)(cbase + (size_t)(l0 + lt * 16 + r16) * LSTR
                                        + k0 + quad * 8);
#pragma unroll
            for (int mt = 0; mt < 2; mt++)
#pragma unroll
                for (int lt = 0; lt < 2; lt++)
                    c[mt][lt] = mfma8(a[mt], bv[lt], c[mt][lt]);
        }
#pragma unroll
        for (int mt = 0; mt < 2; mt++)
#pragma unroll
            for (int lt = 0; lt < 2; lt++)
#pragma unroll
                for (int r = 0; r < 4; r++)
                    sS[(n * 32 + mt * 16 + quad * 4 + r) * 65 + l0 + lt * 16 + r16]
                        = c[mt][lt][r];
    }
    __syncthreads();

    // ---- softmax over l, P = fp8(16 * p / S). s = D/4 (q was /4, ctx x16).
    if (tid < 128) {
        int n = tid >> 5, t = tid & 31;
        const float* row = &sS[(n * 32 + t) * 65];
        float sum = 0.f;
        for (int l = 0; l < 64; l++)
            sum += __expf(fminf(row[l] * 0.25f, 60.f));
        float inv = 16.0f / sum;
        unsigned char* pr = &sP[(n * 32 + t) * 72];
        for (int l = 0; l < 64; l++)
            pr[l] = f32_to_fp8(__expf(fminf(row[l] * 0.25f, 60.f)) * inv);
    }
    __syncthreads();

    // ---- GEMM2: wave w -> e-range [w*128, w*128+128), loop n, pool in regs
    {
        int e0 = w * 128;
        f32x4 pool[2][8];
#pragma unroll
        for (int mt = 0; mt < 2; mt++)
#pragma unroll
            for (int et = 0; et < 8; et++)
#pragma unroll
                for (int r = 0; r < 4; r++) pool[mt][et][r] = -3.4e38f;

        for (int n = 0; n < 4; n++) {
            f32x4 c[2][8] = {};
            const unsigned char* tbase = ctxT8 + (size_t)(b * 4 + n) * 1024 * 64;
#pragma unroll
            for (int k0 = 0; k0 < 64; k0 += 32) {
                long a[2];
#pragma unroll
                for (int mt = 0; mt < 2; mt++)
                    __builtin_memcpy(&a[mt], &sP[(n * 32 + mt * 16 + r16) * 72 + k0 + quad * 8], 8);
#pragma unroll
                for (int et = 0; et < 8; et++) {
                    long bv = *(const long*)(tbase + (size_t)(e0 + et * 16 + r16) * 64
                                             + k0 + quad * 8);
#pragma unroll
                    for (int mt = 0; mt < 2; mt++)
                        c[mt][et] = mfma8(a[mt], bv, c[mt][et]);
                }
            }
#pragma unroll
            for (int mt = 0; mt < 2; mt++)
#pragma unroll
                for (int et = 0; et < 8; et++)
#pragma unroll
                    for (int r = 0; r < 4; r++)
                        pool[mt][et][r] = fmaxf(pool[mt][et][r], c[mt][et][r] * (1.0f / 256.0f));
        }
        __syncthreads();   // sQ8/sS dead; safe to overwrite via sPool
#pragma unroll
        for (int mt = 0; mt < 2; mt++)
#pragma unroll
            for (int et = 0; et < 8; et++)
#pragma unroll
                for (int r = 0; r < 4; r++) {
                    int t = mt * 16 + quad * 4 + r;
                    int e = e0 + et * 16 + r16;
                    __hip_bfloat16 hb = __float2bfloat16(pool[mt][et][r]);
                    sPool[t * 1032 + e] = *(ushort_t*)&hb;
                }
    }
    __syncthreads();

    // ---- GEMM3 logits: wave w -> (mt = w&1, pt = w>>1)
    {
        int mt = w & 1, pt = w >> 1;
        f32x4 c = {};
        const __hip_bfloat16* hrow = hAll + ((size_t)(mt * 16 + r16) * 256 + b) * 1024;
        const __hip_bfloat16* wrow = WcT + (size_t)(pt * 16 + r16) * 2048;
        for (int k0 = 0; k0 < 2048; k0 += 32) {
            bf16x8 a;
            if (k0 < 1024)
                a = *(const bf16x8*)(hrow + k0 + quad * 8);
            else
                a = *(const bf16x8*)&sPool[(mt * 16 + r16) * 1032 + (k0 - 1024) + quad * 8];
            bf16x8 bv = *(const bf16x8*)(wrow + k0 + quad * 8);
            c = mfma16(a, bv, c);
        }
        __syncthreads();   // sP dead; safe to overwrite via slg
#pragma unroll
        for (int r = 0; r < 4; r++) {
            int t = mt * 16 + quad * 4 + r;
            int p = pt * 16 + r16;
            slg[t * 68 + p] = c[r] + bcomp[p];
        }
    }
    __syncthreads();

    // ---- NLL per t
    if (tid < 32) {
        int t = tid;
        const float* row = &slg[t * 68];
        float m = -3.4e38f;
        for (int p = 0; p < 64; p++) m = fmaxf(m, row[p]);
        float se = 0.f;
        for (int p = 0; p < 64; p++) se += __expf(row[p] - m);
        int a = actions[b * 32 + t];
        nllT[t * 256 + b] = m + __logf(se) - row[a];
    }
}

__global__ void kfinal(const float* __restrict__ nllT, void* __restrict__ out,
                       const int* __restrict__ mode) {
    int i = threadIdx.x;
    float s = 0.f;
#pragma unroll
    for (int t = 0; t < 32; t++) s += nllT[t * 256 + i];
    if (*mode) ((__hip_bfloat16*)out)[i] = __float2bfloat16(s);
    else       ((float*)out)[i] = s;
}

// -----------------------------------------------------------------------------
extern "C" void kernel_launch(void* const* d_in, const int* in_sizes, int n_in,
                              void* d_out, int out_size, void* d_ws, size_t ws_size,
                              hipStream_t stream) {
    const int* exs = (const int*)d_in[0];
    const int* cls = (const int*)d_in[1];
    const void* E_raw     = d_in[2];
    const void* WiF_raw   = d_in[3];
    const void* WhF_raw   = d_in[4];
    const void* bF_raw    = d_in[5];
    const void* WiB_raw   = d_in[6];
    const void* WhB_raw   = d_in[7];
    const void* bB_raw    = d_in[8];
    const void* Wattn_raw = d_in[9];
    const void* Wcomp_raw = d_in[10];
    const void* bcomp_raw = d_in[11];
    const void* vWi_raw   = d_in[12];
    const void* vWh_raw   = d_in[13];
    const void* vb_raw    = d_in[14];
    const void* fe_raw    = d_in[15];
    const int* actions = (const int*)d_in[16];
    (void)in_sizes; (void)n_in; (void)out_size; (void)ws_size;

    char* w = (char*)d_ws;
    size_t off = 0;
    auto take = [&](size_t bytes) -> char* {
        char* p = w + off;
        off = (off + bytes + 255) & ~(size_t)255;
        return p;
    };
    __hip_bfloat16* WhT    = (__hip_bfloat16*)take(2ull * 2048 * 512 * 2);
    __hip_bfloat16* WiT    = (__hip_bfloat16*)take(2ull * 2048 * 256 * 2);
    __hip_bfloat16* vWhT   = (__hip_bfloat16*)take(4096ull * 1024 * 2);
    __hip_bfloat16* vWiT   = (__hip_bfloat16*)take(4096ull * 1024 * 2);
    __hip_bfloat16* WattnT = (__hip_bfloat16*)take(1024ull * 1024 * 2);
    __hip_bfloat16* WcT    = (__hip_bfloat16*)take(64ull * 2048 * 2);
    __hip_bfloat16* Ebf    = (__hip_bfloat16*)take(128ull * 128 * 2);
    __hip_bfloat16* febf   = (__hip_bfloat16*)take(32ull * 1024 * 2);
    float* bFf   = (float*)take(2048 * 4);
    float* bBf   = (float*)take(2048 * 4);
    float* bcf   = (float*)take(64 * 4);
    float* vbf   = (float*)take(4096 * 4);
    float* Gtab  = (float*)take(4ull * 128 * 2048 * 4);
    float* VX    = (float*)take(32ull * 4096 * 4);
    __hip_bfloat16* hEnc = (__hip_bfloat16*)take(2ull * 2 * 1024 * 512 * 2); // [buf][dir][1024][512]
    float* cEnc = (float*)take(2ull * 1024 * 512 * 4);
    __hip_bfloat16* hAll = (__hip_bfloat16*)take(33ull * 256 * 1024 * 2);    // h_0..h_32
    float* cDec = (float*)take(256ull * 1024 * 4);
    float* qall = (float*)take(32ull * 256 * 1024 * 4);
    float* nllT = (float*)take(32ull * 256 * 4);
    int*   mode = (int*)take(256);
    unsigned char* ctx8  = (unsigned char*)take(64ull * 1024 * 1024);  // fp8 [l][b4n][e]
    unsigned char* ctxT8 = (unsigned char*)take(64ull * 1024 * 1024);  // fp8 [b4n][e][l]

    (void)hipMemsetAsync(hEnc, 0, 2ull * 1024 * 512 * 2, stream);  // h buf0, both dirs
    (void)hipMemsetAsync(cEnc, 0, 2ull * 1024 * 512 * 4, stream);

    kdetect<<<1, 128, 0, stream>>>((const unsigned int*)E_raw, mode);

    // fused dtype conversions (one launch)
    {
        CvtArgs ca;
        ca.src[0] = E_raw;     ca.dst[0] = Ebf;  ca.n[0] = 128 * 128;  ca.bf16out[0] = 1;
        ca.src[1] = fe_raw;    ca.dst[1] = febf; ca.n[1] = 32 * 1024;  ca.bf16out[1] = 1;
        ca.src[2] = bF_raw;    ca.dst[2] = bFf;  ca.n[2] = 2048;       ca.bf16out[2] = 0;
        ca.src[3] = bB_raw;    ca.dst[3] = bBf;  ca.n[3] = 2048;       ca.bf16out[3] = 0;
        ca.src[4] = bcomp_raw; ca.dst[4] = bcf;  ca.n[4] = 64;         ca.bf16out[4] = 0;
        ca.src[5] = vb_raw;    ca.dst[5] = vbf;  ca.n[5] = 4096;       ca.bf16out[5] = 0;
        kcvt_all<<<dim3(128, 6), 256, 0, stream>>>(ca, mode);
    }

    // fused transposes (one launch)
    {
        TransArgs ta;
        ta.src[0] = WhF_raw;   ta.dst[0] = WhT;              ta.R[0] = 512;  ta.C[0] = 2048;
        ta.src[1] = WhB_raw;   ta.dst[1] = WhT + 2048 * 512; ta.R[1] = 512;  ta.C[1] = 2048;
        ta.src[2] = WiF_raw;   ta.dst[2] = WiT;              ta.R[2] = 256;  ta.C[2] = 2048;
        ta.src[3] = WiB_raw;   ta.dst[3] = WiT + 2048 * 256; ta.R[3] = 256;  ta.C[3] = 2048;
        ta.src[4] = vWh_raw;   ta.dst[4] = vWhT;             ta.R[4] = 1024; ta.C[4] = 4096;
        ta.src[5] = vWi_raw;   ta.dst[5] = vWiT;             ta.R[5] = 1024; ta.C[5] = 4096;
        ta.src[6] = Wattn_raw; ta.dst[6] = WattnT;           ta.R[6] = 1024; ta.C[6] = 1024;
        ta.src[7] = Wcomp_raw; ta.dst[7] = WcT;              ta.R[7] = 2048; ta.C[7] = 64;
        ktrans_all<<<dim3(64, 32, 8), 256, 0, stream>>>(ta, mode);
    }

    // fused Gtab + VX prep (one launch)
    kprep_all<<<288, 256, 0, stream>>>(Ebf, WiT, bFf, bBf, Gtab, febf, vWiT, vbf, VX);

    const size_t HB = 2ull * 1024 * 512;
    for (int t = 0; t < 64; t++) {
        kenc_step<<<512, 256, 0, stream>>>(t, WhT, Gtab, exs, cls,
                                           hEnc + (size_t)(t & 1) * HB,
                                           hEnc + (size_t)((t + 1) & 1) * HB,
                                           cEnc, ctx8);
    }
    // fused ctx transpose + decoder init (one launch)
    ktrans8_init<<<16384 + 1024, 256, 0, stream>>>(ctx8, ctxT8, hEnc, cEnc, hAll, cDec);

    const size_t HD = 256ull * 1024;
    for (int t = 0; t < 32; t++) {
        kdec_gemm<<<256, 256, 0, stream>>>(t, vWhT, WattnT, VX,
                                           hAll + (size_t)t * HD,
                                           hAll + (size_t)(t + 1) * HD,
                                           cDec, qall + (size_t)t * HD);
    }
    kattn_mfma<<<256, 512, 0, stream>>>(qall, ctx8, ctxT8, hAll, WcT, bcf,
                                        actions, nllT);
    kfinal<<<1, 256, 0, stream>>>(nllT, d_out, mode);
}

// Round 10
// 1454.052 us; speedup vs baseline: 1.0466x; 1.0466x over previous
//
#include <hip/hip_runtime.h>
#include <hip/hip_bf16.h>

typedef __bf16 bf16x8 __attribute__((ext_vector_type(8)));
typedef float  f32x4  __attribute__((ext_vector_type(4)));
typedef float  f32x2  __attribute__((ext_vector_type(2)));
typedef unsigned int u32x4 __attribute__((ext_vector_type(4)));
typedef unsigned short ushort_t;
static_assert(sizeof(bf16x8) == 16, "bf16x8 must be 16B");

#define DEV __device__ __forceinline__

DEV f32x4 mfma16(bf16x8 a, bf16x8 b, f32x4 c) {
    return __builtin_amdgcn_mfma_f32_16x16x32_bf16(a, b, c, 0, 0, 0);
}
DEV f32x4 mfma8(long a, long b, f32x4 c) {
    return __builtin_amdgcn_mfma_f32_16x16x32_fp8_fp8(a, b, c, 0, 0, 0);
}
DEV float sigm(float x)   { return 1.0f / (1.0f + __expf(-x)); }
DEV float tanh_f(float x) { return 2.0f / (1.0f + __expf(-2.0f * x)) - 1.0f; }

// async global->LDS, 16B per lane; lds dest must be wave-uniform base (+lane*16)
DEV void glds16(const __hip_bfloat16* g, __hip_bfloat16* l) {
    __builtin_amdgcn_global_load_lds(
        (const __attribute__((address_space(1))) unsigned int*)g,
        (__attribute__((address_space(3))) unsigned int*)l, 16, 0, 0);
}

DEV unsigned char f32_to_fp8(float v) {
    int p = __builtin_amdgcn_cvt_pk_fp8_f32(v, v, 0, false);
    return (unsigned char)(p & 0xFF);
}

DEV int i4get(const int4& v, int r) {
    return r == 0 ? v.x : r == 1 ? v.y : r == 2 ? v.z : v.w;
}

// ---------------- dtype detection: 1 = inputs are bf16, 0 = inputs are fp32 --
__global__ __launch_bounds__(128) void kdetect(const unsigned int* __restrict__ raw,
                                               int* __restrict__ mode) {
    __shared__ int cnt;
    if (threadIdx.x == 0) cnt = 0;
    __syncthreads();
    unsigned int w = raw[threadIdx.x];
    unsigned short lo = (unsigned short)(w & 0xFFFFu);
    unsigned int f32bits = ((unsigned int)lo) << 16;
    float v;
    __builtin_memcpy(&v, &f32bits, 4);
    float a = fabsf(v);
    if (a >= 1e-4f && a <= 1.0f) atomicAdd(&cnt, 1);
    __syncthreads();
    if (threadIdx.x == 0) *mode = (cnt >= 64) ? 1 : 0;
}

// ---------------- fused dtype conversions (6 segments in one launch) ---------
struct CvtArgs {
    const void* src[6];
    void* dst[6];
    int n[6];
    int bf16out[6];
};
__global__ __launch_bounds__(256) void kcvt_all(CvtArgs a, const int* __restrict__ mode) {
    int seg = blockIdx.y;
    int i = blockIdx.x * 256 + threadIdx.x;
    if (i >= a.n[seg]) return;
    int m = *mode;
    if (a.bf16out[seg]) {
        __hip_bfloat16* d = (__hip_bfloat16*)a.dst[seg];
        d[i] = m ? ((const __hip_bfloat16*)a.src[seg])[i]
                 : __float2bfloat16(((const float*)a.src[seg])[i]);
    } else {
        float* d = (float*)a.dst[seg];
        d[i] = m ? __bfloat162float(((const __hip_bfloat16*)a.src[seg])[i])
                 : ((const float*)a.src[seg])[i];
    }
}

// ---------- fused tiled transpose+convert: 8 tensors in one launch -----------
// out_bf16[c][r] = (bf16)in[r][c]; blockIdx.z selects the tensor.
struct TransArgs {
    const void* src[8];
    __hip_bfloat16* dst[8];
    int R[8];
    int C[8];
};
__global__ __launch_bounds__(256) void ktrans_all(TransArgs a, const int* __restrict__ mode) {
    __shared__ float tile[64][65];
    int id = blockIdx.z;
    int R = a.R[id], C = a.C[id];
    int c0 = blockIdx.x * 64, r0 = blockIdx.y * 64;
    if (c0 >= C || r0 >= R) return;
    const void* src = a.src[id];
    __hip_bfloat16* out = a.dst[id];
    int tx = threadIdx.x & 63, ty = threadIdx.x >> 6;
    int m = *mode;
#pragma unroll
    for (int i = ty; i < 64; i += 4) {
        size_t ix = (size_t)(r0 + i) * C + (c0 + tx);
        tile[i][tx] = m ? __bfloat162float(((const __hip_bfloat16*)src)[ix])
                        : ((const float*)src)[ix];
    }
    __syncthreads();
#pragma unroll
    for (int i = ty; i < 64; i += 4)
        out[(size_t)(c0 + i) * R + (r0 + tx)] = __float2bfloat16(tile[tx][i]);
}

// ---- fused prep: blocks 0..255 = Gtab (E@Wi + b), 256..287 = VX (fe@vWi+vb) --
__global__ __launch_bounds__(256) void kprep_all(
    const __hip_bfloat16* __restrict__ E,     // [128][128]
    const __hip_bfloat16* __restrict__ WiT,   // [2][2048][256]
    const float* __restrict__ bF,
    const float* __restrict__ bB,
    float* __restrict__ G,                    // [4][128][512][4]
    const __hip_bfloat16* __restrict__ fe,    // [32][1024]
    const __hip_bfloat16* __restrict__ vWiT,  // [4096][1024]
    const float* __restrict__ vb,             // [4096]
    float* __restrict__ VX)                   // [32][4096]
{
    int lane = threadIdx.x & 63, wid = threadIdx.x >> 6;
    int r16 = lane & 15, quad = lane >> 4;

    if (blockIdx.x < 256) {
        int bid = blockIdx.x;
        int dh = bid >> 6;
        int dir = dh >> 1, half = dh & 1;
        int m0 = ((bid >> 5) & 1) * 64;
        int n0 = (bid & 31) * 64;
        int wrow = wid >> 1, wcol = wid & 1;

        f32x4 acc[2][2] = {};
        const __hip_bfloat16* Ap = E + (size_t)(m0 + wrow * 32 + r16) * 128 + quad * 8;
        const __hip_bfloat16* Bp = WiT + (size_t)dir * 2048 * 256
                                 + (size_t)(n0 + wcol * 32 + r16) * 256 + half * 128 + quad * 8;
#pragma unroll
        for (int kb = 0; kb < 128; kb += 32) {
            bf16x8 a0 = *(const bf16x8*)(Ap + kb);
            bf16x8 a1 = *(const bf16x8*)(Ap + 16 * 128 + kb);
            bf16x8 b0 = *(const bf16x8*)(Bp + kb);
            bf16x8 b1 = *(const bf16x8*)(Bp + 16 * 256 + kb);
            acc[0][0] = mfma16(a0, b0, acc[0][0]);
            acc[0][1] = mfma16(a0, b1, acc[0][1]);
            acc[1][0] = mfma16(a1, b0, acc[1][0]);
            acc[1][1] = mfma16(a1, b1, acc[1][1]);
        }
        const float* bias = dir ? bB : bF;
        float* Gt = G + (size_t)dh * 128 * 2048;
#pragma unroll
        for (int rt = 0; rt < 2; rt++)
#pragma unroll
            for (int ct = 0; ct < 2; ct++)
#pragma unroll
                for (int r = 0; r < 4; r++) {
                    int mm = m0 + wrow * 32 + rt * 16 + quad * 4 + r;
                    int j = n0 + wcol * 32 + ct * 16 + r16;
                    float v = acc[rt][ct][r];
                    if (half == 0) v += bias[j];
                    int g = j >> 9, u = j & 511;
                    Gt[((size_t)mm * 512 + u) * 4 + g] = v;
                }
    } else {
        int n0 = (blockIdx.x - 256) * 128;
        f32x4 acc[2][2] = {};
        const __hip_bfloat16* Ap = fe + (size_t)r16 * 1024 + quad * 8;
        const __hip_bfloat16* Bp = vWiT + (size_t)(n0 + wid * 32 + r16) * 1024 + quad * 8;
        for (int kb = 0; kb < 1024; kb += 32) {
            bf16x8 a0 = *(const bf16x8*)(Ap + kb);
            bf16x8 a1 = *(const bf16x8*)(Ap + 16 * 1024 + kb);
            bf16x8 b0 = *(const bf16x8*)(Bp + kb);
            bf16x8 b1 = *(const bf16x8*)(Bp + 16 * 1024 + kb);
            acc[0][0] = mfma16(a0, b0, acc[0][0]);
            acc[0][1] = mfma16(a0, b1, acc[0][1]);
            acc[1][0] = mfma16(a1, b0, acc[1][0]);
            acc[1][1] = mfma16(a1, b1, acc[1][1]);
        }
#pragma unroll
        for (int rt = 0; rt < 2; rt++)
#pragma unroll
            for (int ct = 0; ct < 2; ct++)
#pragma unroll
                for (int r = 0; r < 4; r++) {
                    int m = rt * 16 + quad * 4 + r;
                    int j = n0 + wid * 32 + ct * 16 + r16;
                    VX[(size_t)m * 4096 + j] = acc[rt][ct][r] + vb[j];
                }
    }
}

// ======== encoder LSTM step: 512 blocks (dir x 16 mt x 16 us), 64m x 32u =====
// Triple-buffered counted-vmcnt pipeline + epilogue prefetch (verified r6-r8).
__global__ __launch_bounds__(256, 2) void kenc_step(
    int t,
    const __hip_bfloat16* __restrict__ WhT,   // [2][2048][512]
    const float* __restrict__ Gtab,           // [4][128][512][4]
    const int* __restrict__ exs,
    const int* __restrict__ cls,
    const __hip_bfloat16* __restrict__ h_in,  // [2][1024][512]
    __hip_bfloat16* __restrict__ h_out,
    float* __restrict__ c_st,                 // [2][1024][512]
    unsigned char* __restrict__ ctx8)         // [64][256][4][1024] fp8 (x16)
{
    __shared__ __align__(16) __hip_bfloat16 sA[3][64 * 64];   // 3 x 8KB
    __shared__ __align__(16) __hip_bfloat16 sB[3][128 * 64];  // 3 x 16KB

    int bid = blockIdx.x;
    int dir = bid >> 8;
    int mt  = (bid >> 4) & 15;
    int us  = bid & 15;
    int l = dir ? (63 - t) : t;
    int m0 = mt * 64, u0 = us * 32;

    int lane = threadIdx.x & 63, w = threadIdx.x >> 6;   // 4 waves
    int wm = w >> 1, wu = w & 1;                          // 2m x 2u
    int r16 = lane & 15, quad = lane >> 4;
    int srow = lane >> 3;
    int scol = ((lane & 7) ^ srow) * 8;   // swizzled global source column

    const __hip_bfloat16* Ab = h_in + (size_t)dir * 1024 * 512;
    const __hip_bfloat16* Bb = WhT + (size_t)dir * 2048 * 512;

    int u = u0 + wu * 16 + r16;
    int mbase = m0 + wm * 32;
    size_t cbase = (size_t)dir * 1024 * 512;
    const float* GeT = Gtab + (size_t)(dir * 2) * 128 * 2048;
    const float* GcT = GeT + 128 * 2048;

    // token prefetch (fast L2 loads; retire before iter-0's counted wait)
    int4 tE0 = *(const int4*)&exs[l * 1024 + mbase + quad * 4];
    int4 tE1 = *(const int4*)&exs[l * 1024 + mbase + 16 + quad * 4];
    int4 tC0 = *(const int4*)&cls[l * 1024 + mbase + quad * 4];
    int4 tC1 = *(const int4*)&cls[l * 1024 + mbase + 16 + quad * 4];

    f32x4 acc[4][2] = {};  // [gate][mi]
    f32x4 geP[2][4], gcP[2][4];
    float cP[2][4];

    auto stage = [&](int buf, int it) {
        int kb = it * 64;
#pragma unroll
        for (int c = 0; c < 2; c++) {
            int r8 = (w * 2 + c) * 8;
            glds16(Ab + (size_t)(m0 + r8 + srow) * 512 + kb + scol,
                   &sA[buf][r8 * 64]);
        }
#pragma unroll
        for (int c = 0; c < 4; c++) {
            int rl = (w * 4 + c) * 8;
            int rr = rl + srow;
            int g = rr >> 5, j = rr & 31;
            glds16(Bb + (size_t)(g * 512 + u0 + j) * 512 + kb + scol,
                   &sB[buf][rl * 64]);
        }
    };

    // prologue: 2 K-tiles in flight (6 ops each per wave)
    stage(0, 0);
    stage(1, 1);

    const int sw = r16 & 7;
    const int NIT = 8;  // 512/64
#pragma unroll
    for (int it = 0; it < NIT; it++) {
        if (it < NIT - 1)
            asm volatile("s_waitcnt vmcnt(6) lgkmcnt(0)" ::: "memory");
        else
            asm volatile("s_waitcnt vmcnt(24) lgkmcnt(0)" ::: "memory");
        __builtin_amdgcn_s_barrier();
        if (it + 2 < NIT) {
            stage((it + 2) % 3, it + 2);
        } else if (it == NIT - 2) {
            // issue epilogue loads: 16 Gtab gathers + 8 c_st reads (24 VMEM)
#pragma unroll
            for (int mi = 0; mi < 2; mi++)
#pragma unroll
                for (int r = 0; r < 4; r++) {
                    int vE = i4get(mi ? tE1 : tE0, r);
                    int vC = i4get(mi ? tC1 : tC0, r);
                    geP[mi][r] = *(const f32x4*)&GeT[((size_t)vE * 512 + u) * 4];
                    gcP[mi][r] = *(const f32x4*)&GcT[((size_t)vC * 512 + u) * 4];
                    int m = mbase + mi * 16 + quad * 4 + r;
                    cP[mi][r] = c_st[cbase + (size_t)m * 512 + u];
                }
        }
        const int buf = it % 3;   // compile-time after full unroll
#pragma unroll
        for (int k32 = 0; k32 < 64; k32 += 32) {
            int co = (((k32 >> 3) + quad) ^ sw) * 8;   // swizzled ds_read column
            bf16x8 a[2], bf[4];
#pragma unroll
            for (int mi = 0; mi < 2; mi++)
                a[mi] = *(const bf16x8*)&sA[buf][(wm * 32 + mi * 16 + r16) * 64 + co];
#pragma unroll
            for (int g = 0; g < 4; g++)
                bf[g] = *(const bf16x8*)&sB[buf][(g * 32 + wu * 16 + r16) * 64 + co];
#pragma unroll
            for (int g = 0; g < 4; g++)
#pragma unroll
                for (int mi = 0; mi < 2; mi++)
                    acc[g][mi] = mfma16(a[mi], bf[g], acc[g][mi]);
        }
    }

    // epilogue: thread owns u, 8 m's; all inputs prefetched
#pragma unroll
    for (int mi = 0; mi < 2; mi++)
#pragma unroll
        for (int r = 0; r < 4; r++) {
            int m = mbase + mi * 16 + quad * 4 + r;
            f32x4 ge = geP[mi][r];
            f32x4 gc = gcP[mi][r];
            float gi = acc[0][mi][r] + ge[0] + gc[0];
            float gf = acc[1][mi][r] + ge[1] + gc[1];
            float gg = acc[2][mi][r] + ge[2] + gc[2];
            float go = acc[3][mi][r] + ge[3] + gc[3];
            size_t cix = cbase + (size_t)m * 512 + u;
            float cn = sigm(gf) * cP[mi][r] + sigm(gi) * tanh_f(gg);
            c_st[cix] = cn;
            float hn = sigm(go) * tanh_f(cn);
            h_out[cix] = __float2bfloat16(hn);
            ctx8[(((size_t)l * 256 + (m >> 2)) * 4 + (m & 3)) * 1024 + dir * 512 + u]
                = f32_to_fp8(hn * 16.0f);
        }
}

// ---- fused: fp8 ctx transpose (blocks 0..16383) + decoder init (16384..17407)
__global__ __launch_bounds__(256) void ktrans8_init(
    const unsigned char* __restrict__ ctx8,
    unsigned char* __restrict__ ctxT8,
    const __hip_bfloat16* __restrict__ hf,  // final h (buf0): [2][1024][512]
    const float* __restrict__ cf,
    __hip_bfloat16* __restrict__ h0,        // [256][1024] (hAll[0])
    float* __restrict__ c0)
{
    __shared__ unsigned int tile[64][17];
    int bx = blockIdx.x;
    int tid = threadIdx.x;
    if (bx < 16384) {
        int b4n = bx & 1023;
        int e0 = (bx >> 10) * 64;
#pragma unroll
        for (int pass = 0; pass < 4; pass++) {
            int idx = pass * 256 + tid;
            int l = idx >> 4, c = idx & 15;
            tile[l][c] = *(const unsigned int*)(ctx8 + (size_t)l * (1024 * 1024)
                                                + (size_t)b4n * 1024 + e0 + c * 4);
        }
        __syncthreads();
        const unsigned char* tb = (const unsigned char*)tile;
#pragma unroll
        for (int pass = 0; pass < 4; pass++) {
            int idx = pass * 256 + tid;
            int e = idx >> 4, c = idx & 15;
            unsigned int v = 0;
#pragma unroll
            for (int j = 0; j < 4; j++) {
                unsigned int byte = tb[(size_t)(c * 4 + j) * 68 + e];
                v |= byte << (8 * j);
            }
            *(unsigned int*)(ctxT8 + ((size_t)b4n * 1024 + e0 + e) * 64 + c * 4) = v;
        }
    } else {
        int idx = (bx - 16384) * 256 + tid;
        int b = idx >> 10, e = idx & 1023;
        int dir = e >> 9, u = e & 511;
        const __hip_bfloat16* hs = hf + (size_t)dir * 1024 * 512;
        const float* cs = cf + (size_t)dir * 1024 * 512;
        float hv = -3.4e38f, cv = -3.4e38f;
#pragma unroll
        for (int n = 0; n < 4; n++) {
            size_t ix = (size_t)(b * 4 + n) * 512 + u;
            hv = fmaxf(hv, __bfloat162float(hs[ix]));
            cv = fmaxf(cv, cs[ix]);
        }
        h0[idx] = __float2bfloat16(hv);
        c0[idx] = cv;
    }
}

// ======== decoder fused GEMM: cell (0..127: 64m x 32u) + q (128..255) ========
// Cell: counted-vmcnt pipeline + epilogue prefetch. Q: counted vmcnt(3).
__global__ __launch_bounds__(256, 2) void kdec_gemm(
    int t,
    const __hip_bfloat16* __restrict__ vWhT,   // [4096][1024]
    const __hip_bfloat16* __restrict__ WattnT, // [1024][1024]
    const float* __restrict__ VX,              // [32][4096]
    const __hip_bfloat16* __restrict__ h_in,   // [256][1024]  (h_t = hAll[t])
    __hip_bfloat16* __restrict__ h_out,        // [256][1024]  (hAll[t+1])
    float* __restrict__ c_st,                  // [256][1024]
    float* __restrict__ qout)                  // [256][1024]  (qall[t])
{
    __shared__ __align__(16) __hip_bfloat16 sA[3][64 * 64];   // 3 x 8KB
    __shared__ __align__(16) __hip_bfloat16 sB[3][128 * 64];  // 3 x 16KB

    int bid = blockIdx.x;
    int lane = threadIdx.x & 63, w = threadIdx.x >> 6;   // 4 waves
    int wm = w >> 1, wu = w & 1;                          // 2m x 2u/2n
    int r16 = lane & 15, quad = lane >> 4;
    int srow = lane >> 3;
    int scol = ((lane & 7) ^ srow) * 8;   // swizzled global source column
    const int NIT = 16;  // 1024/64
    const int sw = r16 & 7;

    bool cellp = bid < 128;
    int b2 = cellp ? bid : bid - 128;
    int m0 = (b2 >> 5) * 64;       // 4 m-tiles of 64
    int n0 = (b2 & 31) * 32;       // 32 u/n-tiles of 32
    int u = n0 + wu * 16 + r16;
    int mbase = m0 + wm * 32;

    if (cellp) {
        f32x4 acc[4][2] = {};
        float vxP[4], cP[2][4];
        const float* vx = VX + (size_t)t * 4096;
        auto stage = [&](int buf, int it) {
            int kb = it * 64;
#pragma unroll
            for (int c = 0; c < 2; c++) {
                int r8 = (w * 2 + c) * 8;
                glds16(h_in + (size_t)(m0 + r8 + srow) * 1024 + kb + scol,
                       &sA[buf][r8 * 64]);
            }
#pragma unroll
            for (int c = 0; c < 4; c++) {
                int rl = (w * 4 + c) * 8;
                int rr = rl + srow;
                int g = rr >> 5, j = rr & 31;
                glds16(vWhT + (size_t)(g * 1024 + n0 + j) * 1024 + kb + scol,
                       &sB[buf][rl * 64]);
            }
        };
        stage(0, 0);
        stage(1, 1);
#pragma unroll
        for (int it = 0; it < NIT; it++) {
            if (it < NIT - 1)
                asm volatile("s_waitcnt vmcnt(6) lgkmcnt(0)" ::: "memory");
            else
                asm volatile("s_waitcnt vmcnt(12) lgkmcnt(0)" ::: "memory");
            __builtin_amdgcn_s_barrier();
            if (it + 2 < NIT) {
                stage((it + 2) % 3, it + 2);
            } else if (it == NIT - 2) {
                // issue epilogue loads: 4 VX + 8 c_st (12 VMEM)
                vxP[0] = vx[u];
                vxP[1] = vx[1024 + u];
                vxP[2] = vx[2048 + u];
                vxP[3] = vx[3072 + u];
#pragma unroll
                for (int mi = 0; mi < 2; mi++)
#pragma unroll
                    for (int r = 0; r < 4; r++) {
                        int m = mbase + mi * 16 + quad * 4 + r;
                        cP[mi][r] = c_st[(size_t)m * 1024 + u];
                    }
            }
            const int buf = it % 3;
#pragma unroll
            for (int k32 = 0; k32 < 64; k32 += 32) {
                int co = (((k32 >> 3) + quad) ^ sw) * 8;
                bf16x8 a[2], bf[4];
#pragma unroll
                for (int mi = 0; mi < 2; mi++)
                    a[mi] = *(const bf16x8*)&sA[buf][(wm * 32 + mi * 16 + r16) * 64 + co];
#pragma unroll
                for (int g = 0; g < 4; g++)
                    bf[g] = *(const bf16x8*)&sB[buf][(g * 32 + wu * 16 + r16) * 64 + co];
#pragma unroll
                for (int g = 0; g < 4; g++)
#pragma unroll
                    for (int mi = 0; mi < 2; mi++)
                        acc[g][mi] = mfma16(a[mi], bf[g], acc[g][mi]);
            }
        }
#pragma unroll
        for (int mi = 0; mi < 2; mi++)
#pragma unroll
            for (int r = 0; r < 4; r++) {
                int m = mbase + mi * 16 + quad * 4 + r;
                float gi = acc[0][mi][r] + vxP[0];
                float gf = acc[1][mi][r] + vxP[1];
                float gg = acc[2][mi][r] + vxP[2];
                float go = acc[3][mi][r] + vxP[3];
                size_t cix = (size_t)m * 1024 + u;
                float cn = sigm(gf) * cP[mi][r] + sigm(gi) * tanh_f(gg);
                c_st[cix] = cn;
                h_out[cix] = __float2bfloat16(sigm(go) * tanh_f(cn));
            }
    } else {
        f32x4 acc[2] = {};
        auto stage = [&](int buf, int it) {
            int kb = it * 64;
#pragma unroll
            for (int c = 0; c < 2; c++) {
                int r8 = (w * 2 + c) * 8;
                glds16(h_in + (size_t)(m0 + r8 + srow) * 1024 + kb + scol,
                       &sA[buf][r8 * 64]);
            }
            {
                int rl = w * 8;
                glds16(WattnT + (size_t)(n0 + rl + srow) * 1024 + kb + scol,
                       &sB[buf][rl * 64]);
            }
        };
        stage(0, 0);
        stage(1, 1);
#pragma unroll
        for (int it = 0; it < NIT; it++) {
            if (it < NIT - 1)
                asm volatile("s_waitcnt vmcnt(3) lgkmcnt(0)" ::: "memory");
            else
                asm volatile("s_waitcnt vmcnt(0) lgkmcnt(0)" ::: "memory");
            __builtin_amdgcn_s_barrier();
            if (it + 2 < NIT) stage((it + 2) % 3, it + 2);
            const int buf = it % 3;
#pragma unroll
            for (int k32 = 0; k32 < 64; k32 += 32) {
                int co = (((k32 >> 3) + quad) ^ sw) * 8;
                bf16x8 a[2];
#pragma unroll
                for (int mi = 0; mi < 2; mi++)
                    a[mi] = *(const bf16x8*)&sA[buf][(wm * 32 + mi * 16 + r16) * 64 + co];
                bf16x8 bf = *(const bf16x8*)&sB[buf][(wu * 16 + r16) * 64 + co];
#pragma unroll
                for (int mi = 0; mi < 2; mi++)
                    acc[mi] = mfma16(a[mi], bf, acc[mi]);
            }
        }
        int n = n0 + wu * 16 + r16;
#pragma unroll
        for (int mi = 0; mi < 2; mi++)
#pragma unroll
            for (int r = 0; r < 4; r++) {
                int m = mbase + mi * 16 + quad * 4 + r;
                qout[(size_t)m * 1024 + n] = acc[mi][r];
            }
    }
}

// ======== MFMA attention: block = b, all 32 t batched ========================
// LDS phase-aliased (peak 75520 B -> 2 blocks/CU, was 147KB @ 1 block/CU).
// __launch_bounds__(512, 2): r9's (512,4) capped VGPR at 64 -> 73MB scratch
// spill (WRITE_SIZE counter). (512,2) restores ~116 VGPR; LDS now the
// occupancy limiter at 2 blocks/CU.
__global__ __launch_bounds__(512, 2) void kattn_mfma(
    const float* __restrict__ qall,           // [32][256][1024]
    const unsigned char* __restrict__ ctx8,   // [64][1024][1024] fp8 (x16)
    const unsigned char* __restrict__ ctxT8,  // [1024][1024][64] fp8 (x16)
    const __hip_bfloat16* __restrict__ hAll,  // [33][256][1024]
    const __hip_bfloat16* __restrict__ WcT,   // [64][2048]
    const float* __restrict__ bcomp,          // [64]
    const int* __restrict__ actions,          // [256][32]
    float* __restrict__ nllT)                 // [32][256]
{
    __shared__ __align__(16) char smem[75520];
    unsigned char* sQ8   = (unsigned char*)smem;             // 32*1032, stride 1032
    float*         sS    = (float*)(smem + 33024);           // [n*32+t][65]
    unsigned char* sP    = (unsigned char*)(smem + 66304);   // 4*32*72
    ushort_t*      sPool = (ushort_t*)smem;                  // 32*1032 (aliases sQ8+sS)
    float*         slg   = (float*)(smem + 66304);           // 32*68 (aliases sP)

    int b = blockIdx.x;
    int tid = threadIdx.x;
    int lane = tid & 63, w = tid >> 6;
    int r16 = lane & 15, quad = lane >> 4;
    const size_t LSTR = 1024 * 1024;

    // ---- phase Q: qall fp32 -> fp8 (x 1/4) into LDS
    for (int i = 0; i < 64; i++) {
        int idx = i * 512 + tid;           // coalesced over tid
        int t = idx >> 10, e = idx & 1023;
        float v = qall[((size_t)t * 256 + b) * 1024 + e] * 0.25f;
        sQ8[t * 1032 + e] = f32_to_fp8(v);
    }
    __syncthreads();

    // ---- GEMM1: wave w -> (n = w>>1, l-half lh = w&1)
    {
        int n = w >> 1, lh = w & 1;
        int l0 = lh * 32;
        f32x4 c[2][2] = {};
        const unsigned char* cbase = ctx8 + (size_t)(b * 4 + n) * 1024;
        for (int k0 = 0; k0 < 1024; k0 += 32) {
            long a[2], bv[2];
#pragma unroll
            for (int mt = 0; mt < 2; mt++)
                __builtin_memcpy(&a[mt], &sQ8[(mt * 16 + r16) * 1032 + k0 + quad * 8], 8);
#pragma unroll
            for (int lt = 0; lt < 2; lt++)
                bv[lt] = *(const long*)(cbase + (size_t)(l0 + lt * 16 + r16) * LSTR
                                        + k0 + quad * 8);
#pragma unroll
            for (int mt = 0; mt < 2; mt++)
#pragma unroll
                for (int lt = 0; lt < 2; lt++)
                    c[mt][lt] = mfma8(a[mt], bv[lt], c[mt][lt]);
        }
#pragma unroll
        for (int mt = 0; mt < 2; mt++)
#pragma unroll
            for (int lt = 0; lt < 2; lt++)
#pragma unroll
                for (int r = 0; r < 4; r++)
                    sS[(n * 32 + mt * 16 + quad * 4 + r) * 65 + l0 + lt * 16 + r16]
                        = c[mt][lt][r];
    }
    __syncthreads();

    // ---- softmax over l, P = fp8(16 * p / S). s = D/4 (q was /4, ctx x16).
    if (tid < 128) {
        int n = tid >> 5, t = tid & 31;
        const float* row = &sS[(n * 32 + t) * 65];
        float sum = 0.f;
        for (int l = 0; l < 64; l++)
            sum += __expf(fminf(row[l] * 0.25f, 60.f));
        float inv = 16.0f / sum;
        unsigned char* pr = &sP[(n * 32 + t) * 72];
        for (int l = 0; l < 64; l++)
            pr[l] = f32_to_fp8(__expf(fminf(row[l] * 0.25f, 60.f)) * inv);
    }
    __syncthreads();

    // ---- GEMM2: wave w -> e-range [w*128, w*128+128), loop n, pool in regs
    {
        int e0 = w * 128;
        f32x4 pool[2][8];
#pragma unroll
        for (int mt = 0; mt < 2; mt++)
#pragma unroll
            for (int et = 0; et < 8; et++)
#pragma unroll
                for (int r = 0; r < 4; r++) pool[mt][et][r] = -3.4e38f;

        for (int n = 0; n < 4; n++) {
            f32x4 c[2][8] = {};
            const unsigned char* tbase = ctxT8 + (size_t)(b * 4 + n) * 1024 * 64;
#pragma unroll
            for (int k0 = 0; k0 < 64; k0 += 32) {
                long a[2];
#pragma unroll
                for (int mt = 0; mt < 2; mt++)
                    __builtin_memcpy(&a[mt], &sP[(n * 32 + mt * 16 + r16) * 72 + k0 + quad * 8], 8);
#pragma unroll
                for (int et = 0; et < 8; et++) {
                    long bv = *(const long*)(tbase + (size_t)(e0 + et * 16 + r16) * 64
                                             + k0 + quad * 8);
#pragma unroll
                    for (int mt = 0; mt < 2; mt++)
                        c[mt][et] = mfma8(a[mt], bv, c[mt][et]);
                }
            }
#pragma unroll
            for (int mt = 0; mt < 2; mt++)
#pragma unroll
                for (int et = 0; et < 8; et++)
#pragma unroll
                    for (int r = 0; r < 4; r++)
                        pool[mt][et][r] = fmaxf(pool[mt][et][r], c[mt][et][r] * (1.0f / 256.0f));
        }
        __syncthreads();   // sQ8/sS dead; safe to overwrite via sPool
#pragma unroll
        for (int mt = 0; mt < 2; mt++)
#pragma unroll
            for (int et = 0; et < 8; et++)
#pragma unroll
                for (int r = 0; r < 4; r++) {
                    int t = mt * 16 + quad * 4 + r;
                    int e = e0 + et * 16 + r16;
                    __hip_bfloat16 hb = __float2bfloat16(pool[mt][et][r]);
                    sPool[t * 1032 + e] = *(ushort_t*)&hb;
                }
    }
    __syncthreads();

    // ---- GEMM3 logits: wave w -> (mt = w&1, pt = w>>1)
    {
        int mt = w & 1, pt = w >> 1;
        f32x4 c = {};
        const __hip_bfloat16* hrow = hAll + ((size_t)(mt * 16 + r16) * 256 + b) * 1024;
        const __hip_bfloat16* wrow = WcT + (size_t)(pt * 16 + r16) * 2048;
        for (int k0 = 0; k0 < 2048; k0 += 32) {
            bf16x8 a;
            if (k0 < 1024)
                a = *(const bf16x8*)(hrow + k0 + quad * 8);
            else
                a = *(const bf16x8*)&sPool[(mt * 16 + r16) * 1032 + (k0 - 1024) + quad * 8];
            bf16x8 bv = *(const bf16x8*)(wrow + k0 + quad * 8);
            c = mfma16(a, bv, c);
        }
        __syncthreads();   // sP dead; safe to overwrite via slg
#pragma unroll
        for (int r = 0; r < 4; r++) {
            int t = mt * 16 + quad * 4 + r;
            int p = pt * 16 + r16;
            slg[t * 68 + p] = c[r] + bcomp[p];
        }
    }
    __syncthreads();

    // ---- NLL per t
    if (tid < 32) {
        int t = tid;
        const float* row = &slg[t * 68];
        float m = -3.4e38f;
        for (int p = 0; p < 64; p++) m = fmaxf(m, row[p]);
        float se = 0.f;
        for (int p = 0; p < 64; p++) se += __expf(row[p] - m);
        int a = actions[b * 32 + t];
        nllT[t * 256 + b] = m + __logf(se) - row[a];
    }
}

__global__ void kfinal(const float* __restrict__ nllT, void* __restrict__ out,
                       const int* __restrict__ mode) {
    int i = threadIdx.x;
    float s = 0.f;
#pragma unroll
    for (int t = 0; t < 32; t++) s += nllT[t * 256 + i];
    if (*mode) ((__hip_bfloat16*)out)[i] = __float2bfloat16(s);
    else       ((float*)out)[i] = s;
}

// -----------------------------------------------------------------------------
extern "C" void kernel_launch(void* const* d_in, const int* in_sizes, int n_in,
                              void* d_out, int out_size, void* d_ws, size_t ws_size,
                              hipStream_t stream) {
    const int* exs = (const int*)d_in[0];
    const int* cls = (const int*)d_in[1];
    const void* E_raw     = d_in[2];
    const void* WiF_raw   = d_in[3];
    const void* WhF_raw   = d_in[4];
    const void* bF_raw    = d_in[5];
    const void* WiB_raw   = d_in[6];
    const void* WhB_raw   = d_in[7];
    const void* bB_raw    = d_in[8];
    const void* Wattn_raw = d_in[9];
    const void* Wcomp_raw = d_in[10];
    const void* bcomp_raw = d_in[11];
    const void* vWi_raw   = d_in[12];
    const void* vWh_raw   = d_in[13];
    const void* vb_raw    = d_in[14];
    const void* fe_raw    = d_in[15];
    const int* actions = (const int*)d_in[16];
    (void)in_sizes; (void)n_in; (void)out_size; (void)ws_size;

    char* w = (char*)d_ws;
    size_t off = 0;
    auto take = [&](size_t bytes) -> char* {
        char* p = w + off;
        off = (off + bytes + 255) & ~(size_t)255;
        return p;
    };
    __hip_bfloat16* WhT    = (__hip_bfloat16*)take(2ull * 2048 * 512 * 2);
    __hip_bfloat16* WiT    = (__hip_bfloat16*)take(2ull * 2048 * 256 * 2);
    __hip_bfloat16* vWhT   = (__hip_bfloat16*)take(4096ull * 1024 * 2);
    __hip_bfloat16* vWiT   = (__hip_bfloat16*)take(4096ull * 1024 * 2);
    __hip_bfloat16* WattnT = (__hip_bfloat16*)take(1024ull * 1024 * 2);
    __hip_bfloat16* WcT    = (__hip_bfloat16*)take(64ull * 2048 * 2);
    __hip_bfloat16* Ebf    = (__hip_bfloat16*)take(128ull * 128 * 2);
    __hip_bfloat16* febf   = (__hip_bfloat16*)take(32ull * 1024 * 2);
    float* bFf   = (float*)take(2048 * 4);
    float* bBf   = (float*)take(2048 * 4);
    float* bcf   = (float*)take(64 * 4);
    float* vbf   = (float*)take(4096 * 4);
    float* Gtab  = (float*)take(4ull * 128 * 2048 * 4);
    float* VX    = (float*)take(32ull * 4096 * 4);
    __hip_bfloat16* hEnc = (__hip_bfloat16*)take(2ull * 2 * 1024 * 512 * 2); // [buf][dir][1024][512]
    float* cEnc = (float*)take(2ull * 1024 * 512 * 4);
    __hip_bfloat16* hAll = (__hip_bfloat16*)take(33ull * 256 * 1024 * 2);    // h_0..h_32
    float* cDec = (float*)take(256ull * 1024 * 4);
    float* qall = (float*)take(32ull * 256 * 1024 * 4);
    float* nllT = (float*)take(32ull * 256 * 4);
    int*   mode = (int*)take(256);
    unsigned char* ctx8  = (unsigned char*)take(64ull * 1024 * 1024);  // fp8 [l][b4n][e]
    unsigned char* ctxT8 = (unsigned char*)take(64ull * 1024 * 1024);  // fp8 [b4n][e][l]

    (void)hipMemsetAsync(hEnc, 0, 2ull * 1024 * 512 * 2, stream);  // h buf0, both dirs
    (void)hipMemsetAsync(cEnc, 0, 2ull * 1024 * 512 * 4, stream);

    kdetect<<<1, 128, 0, stream>>>((const unsigned int*)E_raw, mode);

    // fused dtype conversions (one launch)
    {
        CvtArgs ca;
        ca.src[0] = E_raw;     ca.dst[0] = Ebf;  ca.n[0] = 128 * 128;  ca.bf16out[0] = 1;
        ca.src[1] = fe_raw;    ca.dst[1] = febf; ca.n[1] = 32 * 1024;  ca.bf16out[1] = 1;
        ca.src[2] = bF_raw;    ca.dst[2] = bFf;  ca.n[2] = 2048;       ca.bf16out[2] = 0;
        ca.src[3] = bB_raw;    ca.dst[3] = bBf;  ca.n[3] = 2048;       ca.bf16out[3] = 0;
        ca.src[4] = bcomp_raw; ca.dst[4] = bcf;  ca.n[4] = 64;         ca.bf16out[4] = 0;
        ca.src[5] = vb_raw;    ca.dst[5] = vbf;  ca.n[5] = 4096;       ca.bf16out[5] = 0;
        kcvt_all<<<dim3(128, 6), 256, 0, stream>>>(ca, mode);
    }

    // fused transposes (one launch)
    {
        TransArgs ta;
        ta.src[0] = WhF_raw;   ta.dst[0] = WhT;              ta.R[0] = 512;  ta.C[0] = 2048;
        ta.src[1] = WhB_raw;   ta.dst[1] = WhT + 2048 * 512; ta.R[1] = 512;  ta.C[1] = 2048;
        ta.src[2] = WiF_raw;   ta.dst[2] = WiT;              ta.R[2] = 256;  ta.C[2] = 2048;
        ta.src[3] = WiB_raw;   ta.dst[3] = WiT + 2048 * 256; ta.R[3] = 256;  ta.C[3] = 2048;
        ta.src[4] = vWh_raw;   ta.dst[4] = vWhT;             ta.R[4] = 1024; ta.C[4] = 4096;
        ta.src[5] = vWi_raw;   ta.dst[5] = vWiT;             ta.R[5] = 1024; ta.C[5] = 4096;
        ta.src[6] = Wattn_raw; ta.dst[6] = WattnT;           ta.R[6] = 1024; ta.C[6] = 1024;
        ta.src[7] = Wcomp_raw; ta.dst[7] = WcT;              ta.R[7] = 2048; ta.C[7] = 64;
        ktrans_all<<<dim3(64, 32, 8), 256, 0, stream>>>(ta, mode);
    }

    // fused Gtab + VX prep (one launch)
    kprep_all<<<288, 256, 0, stream>>>(Ebf, WiT, bFf, bBf, Gtab, febf, vWiT, vbf, VX);

    const size_t HB = 2ull * 1024 * 512;
    for (int t = 0; t < 64; t++) {
        kenc_step<<<512, 256, 0, stream>>>(t, WhT, Gtab, exs, cls,
                                           hEnc + (size_t)(t & 1) * HB,
                                           hEnc + (size_t)((t + 1) & 1) * HB,
                                           cEnc, ctx8);
    }
    // fused ctx transpose + decoder init (one launch)
    ktrans8_init<<<16384 + 1024, 256, 0, stream>>>(ctx8, ctxT8, hEnc, cEnc, hAll, cDec);

    const size_t HD = 256ull * 1024;
    for (int t = 0; t < 32; t++) {
        kdec_gemm<<<256, 256, 0, stream>>>(t, vWhT, WattnT, VX,
                                           hAll + (size_t)t * HD,
                                           hAll + (size_t)(t + 1) * HD,
                                           cDec, qall + (size_t)t * HD);
    }
    kattn_mfma<<<256, 512, 0, stream>>>(qall, ctx8, ctxT8, hAll, WcT, bcf,
                                        actions, nllT);
    kfinal<<<1, 256, 0, stream>>>(nllT, d_out, mode);
}